// Round 2
// baseline (692.122 us; speedup 1.0000x reference)
//
#include <hip/hip_runtime.h>
#include <hip/hip_bf16.h>

typedef __hip_bfloat16 bf16;

#define D 128
#define H 8
#define C 16
#define EDIM 16
#define SQRT_D 11.313708498984761f
#define EPB 8   // edges per block in k_edge

__device__ __forceinline__ float cvt(float v) { return v; }
__device__ __forceinline__ float cvt(bf16 v) { return __bfloat162float(v); }

// ------------------------------------------------------- input dtype detect
// Reads first 4096 uint16 halves of emb. bf16 data: exponent field <= ~125.
// fp32 data: even halves are low mantissa bits -> ~uniform u16 -> ~48% have
// exponent in (132,255). flag = 1 means inputs are fp32.
__global__ void k_detect(const unsigned short* __restrict__ u, int* flag) {
    __shared__ int sh[256];
    int t = threadIdx.x;
    int cnt = 0;
    for (int i = t; i < 4096; i += 256) {
        int e = (u[i] >> 7) & 0xFF;
        cnt += (e > 132 && e < 255) ? 1 : 0;
    }
    sh[t] = cnt;
    __syncthreads();
    for (int s = 128; s > 0; s >>= 1) {
        if (t < s) sh[t] += sh[t + s];
        __syncthreads();
    }
    if (t == 0) *flag = (sh[0] > 100) ? 1 : 0;
}

// ---------------------------------------------------------------- zero fill
__global__ void k_zero(float* p, size_t count) {
    size_t idx = (size_t)blockIdx.x * blockDim.x + threadIdx.x;
    size_t stride = (size_t)gridDim.x * blockDim.x;
    for (size_t i = idx; i < count; i += stride) p[i] = 0.0f;
}

// ------------------------------------------------- node transform: xl / xr
template <typename T>
__device__ __forceinline__ void node_body(
    const int* __restrict__ x, const T* __restrict__ emb,
    const T* __restrict__ Wl, const T* __restrict__ bl,
    const T* __restrict__ Wr, const T* __restrict__ br,
    float* __restrict__ xl, float* __restrict__ xr, int n)
{
    __shared__ float hS[8][D];
    const int t = threadIdx.x;
    const int d = t & (D - 1);
    const int r = t >> 7;
    const int nb = blockIdx.x * 8;

    #pragma unroll
    for (int j = 0; j < 4; ++j) {
        int row = r + 2 * j;
        int node = nb + row;
        float hv = 0.0f;
        if (node < n) {
            int tok = x[node];
            hv = cvt(emb[(size_t)tok * D + d]) * SQRT_D;
        }
        hS[row][d] = hv;
    }
    __syncthreads();

    float accl[4], accr[4];
    const float blv = cvt(bl[d]);
    const float brv = cvt(br[d]);
    #pragma unroll
    for (int j = 0; j < 4; ++j) { accl[j] = blv; accr[j] = brv; }

    for (int k = 0; k < D; ++k) {
        float wl = cvt(Wl[k * D + d]);
        float wr = cvt(Wr[k * D + d]);
        #pragma unroll
        for (int j = 0; j < 4; ++j) {
            float hv = hS[r + 2 * j][k];
            accl[j] += hv * wl;
            accr[j] += hv * wr;
        }
    }

    #pragma unroll
    for (int j = 0; j < 4; ++j) {
        int node = nb + r + 2 * j;
        if (node < n) {
            xl[(size_t)node * D + d] = accl[j];
            xr[(size_t)node * D + d] = accr[j];
        }
    }
}

__global__ __launch_bounds__(256) void k_node(
    const int* x, const void* emb, const void* Wl, const void* bl,
    const void* Wr, const void* br, float* xl, float* xr, int n,
    const int* flag)
{
    if (*flag)
        node_body<float>(x, (const float*)emb, (const float*)Wl, (const float*)bl,
                         (const float*)Wr, (const float*)br, xl, xr, n);
    else
        node_body<bf16>(x, (const bf16*)emb, (const bf16*)Wl, (const bf16*)bl,
                        (const bf16*)Wr, (const bf16*)br, xl, xr, n);
}

// ------------------------------------------------------------- edge pass
// Unnormalized softmax (scores are O(+-8): exp cannot overflow fp32):
// ex = exp(score); denom[dst,h] += ex; aggnum[dst,d] += ex * xl[src,d].
template <typename T>
__device__ __forceinline__ void edge_body(
    const int* __restrict__ ei, const T* __restrict__ ew,
    const T* __restrict__ We, const T* __restrict__ att,
    const float* __restrict__ xl, const float* __restrict__ xr,
    float* __restrict__ denom, float* __restrict__ aggnum, int nE)
{
    const int t = threadIdx.x;
    const int d = t & (D - 1);
    const int sub = t >> 7;
    const int k15 = t & 15;

    float we[EDIM];
    #pragma unroll
    for (int k = 0; k < EDIM; ++k) we[k] = cvt(We[k * D + d]);
    const float attd = cvt(att[d]);

    const long ebase = (long)blockIdx.x * EPB;
    for (int it = 0; it < EPB / 2; ++it) {
        long e = ebase + it * 2 + sub;
        if (e >= nE) continue;
        int src = ei[e];
        int dst = ei[nE + e];

        float ewk = cvt(ew[e * EDIM + k15]);
        float eemb = 0.0f;
        #pragma unroll
        for (int k = 0; k < EDIM; ++k)
            eemb += __shfl(ewk, k, 16) * we[k];

        float xls = xl[(size_t)src * D + d];
        float z = xls + xr[(size_t)dst * D + d] + eemb;
        float m = z > 0.0f ? z : 0.2f * z;       // leaky_relu slope 0.2
        float p = m * attd;

        p += __shfl_xor(p, 8, 16);
        p += __shfl_xor(p, 4, 16);
        p += __shfl_xor(p, 2, 16);
        p += __shfl_xor(p, 1, 16);

        float ex = __expf(p);
        if (k15 == 0) atomicAdd(&denom[(size_t)dst * H + (d >> 4)], ex);
        atomicAdd(&aggnum[(size_t)dst * D + d], ex * xls);
    }
}

__global__ __launch_bounds__(256) void k_edge(
    const int* ei, const void* ew, const void* We, const void* att,
    const float* xl, const float* xr, float* denom, float* aggnum, int nE,
    const int* flag)
{
    if (*flag)
        edge_body<float>(ei, (const float*)ew, (const float*)We, (const float*)att,
                         xl, xr, denom, aggnum, nE);
    else
        edge_body<bf16>(ei, (const bf16*)ew, (const bf16*)We, (const bf16*)att,
                        xl, xr, denom, aggnum, nE);
}

// --------------------------------------------------------- BN statistics
template <typename T>
__device__ __forceinline__ void bnstats_body(
    const float* __restrict__ aggnum, const float* __restrict__ denom,
    const T* __restrict__ bias,
    float* __restrict__ bnsum, float* __restrict__ bnsumsq, int n)
{
    const int t = threadIdx.x;
    const int d = t & (D - 1);
    const int r = t >> 7;
    const float bv = cvt(bias[d]);
    float s = 0.0f, s2 = 0.0f;
    for (int i = blockIdx.x * 2 + r; i < n; i += gridDim.x * 2) {
        float den = denom[(size_t)i * H + (d >> 4)];
        float v = den > 0.0f ? aggnum[(size_t)i * D + d] / den : 0.0f;
        v += bv;
        s += v;
        s2 += v * v;
    }
    __shared__ float sS[2][D], s2S[2][D];
    sS[r][d] = s;
    s2S[r][d] = s2;
    __syncthreads();
    if (r == 0) {
        atomicAdd(&bnsum[d], sS[0][d] + sS[1][d]);
        atomicAdd(&bnsumsq[d], s2S[0][d] + s2S[1][d]);
    }
}

__global__ __launch_bounds__(256) void k_bnstats(
    const float* aggnum, const float* denom, const void* bias,
    float* bnsum, float* bnsumsq, int n, const int* flag)
{
    if (*flag)
        bnstats_body<float>(aggnum, denom, (const float*)bias, bnsum, bnsumsq, n);
    else
        bnstats_body<bf16>(aggnum, denom, (const bf16*)bias, bnsum, bnsumsq, n);
}

// ------------------------------------------------------------- finalize
template <typename T>
__device__ __forceinline__ void final_body(
    const float* __restrict__ aggnum, const float* __restrict__ denom,
    const T* __restrict__ bias, const T* __restrict__ gamma,
    const T* __restrict__ beta,
    const float* __restrict__ bnsum, const float* __restrict__ bnsumsq,
    float* __restrict__ out, int n)
{
    int idx = blockIdx.x * blockDim.x + threadIdx.x;
    if (idx >= n * D) return;
    int d = idx & (D - 1);
    int i = idx >> 7;
    float den = denom[(size_t)i * H + (d >> 4)];
    float v = den > 0.0f ? aggnum[idx] / den : 0.0f;
    v += cvt(bias[d]);
    float invN = 1.0f / (float)n;
    float mean = bnsum[d] * invN;
    float var = bnsumsq[d] * invN - mean * mean;
    float y = (v - mean) * rsqrtf(var + 1e-5f) * cvt(gamma[d]) + cvt(beta[d]);
    y = y > 0.0f ? y : 0.01f * y;   // leaky_relu slope 0.01
    out[idx] = y;                   // OUTPUT IS FP32
}

__global__ __launch_bounds__(256) void k_final(
    const float* aggnum, const float* denom, const void* bias,
    const void* gamma, const void* beta,
    const float* bnsum, const float* bnsumsq, float* out, int n,
    const int* flag)
{
    if (*flag)
        final_body<float>(aggnum, denom, (const float*)bias, (const float*)gamma,
                          (const float*)beta, bnsum, bnsumsq, out, n);
    else
        final_body<bf16>(aggnum, denom, (const bf16*)bias, (const bf16*)gamma,
                         (const bf16*)beta, bnsum, bnsumsq, out, n);
}

// ---------------------------------------------------------------- launch
extern "C" void kernel_launch(void* const* d_in, const int* in_sizes, int n_in,
                              void* d_out, int out_size, void* d_ws, size_t ws_size,
                              hipStream_t stream)
{
    const int*  x     = (const int*)d_in[0];
    const int*  ei    = (const int*)d_in[1];
    const void* ew    = d_in[2];
    const void* emb   = d_in[3];
    const void* Wl    = d_in[4];
    const void* bl    = d_in[5];
    const void* Wr    = d_in[6];
    const void* br    = d_in[7];
    const void* att   = d_in[8];
    const void* We    = d_in[9];
    const void* bias  = d_in[10];
    const void* gamma = d_in[11];
    const void* beta  = d_in[12];

    const int n  = in_sizes[0];        // 50000
    const int nE = in_sizes[1] / 2;    // 800000

    // workspace layout (fp32): xl | xr | aggnum | denom | bnsum | bnsumsq | flag
    float* ws      = (float*)d_ws;
    float* xl      = ws;
    float* xr      = xl + (size_t)n * D;
    float* aggnum  = xr + (size_t)n * D;
    float* denom   = aggnum + (size_t)n * D;
    float* bnsum   = denom + (size_t)n * H;
    float* bnsumsq = bnsum + D;
    int*   flag    = (int*)(bnsumsq + D);

    k_detect<<<1, 256, 0, stream>>>((const unsigned short*)emb, flag);

    size_t zcount = (size_t)n * D + (size_t)n * H + 2 * D;
    k_zero<<<1024, 256, 0, stream>>>(aggnum, zcount);

    k_node<<<(n + 7) / 8, 256, 0, stream>>>(x, emb, Wl, bl, Wr, br, xl, xr, n, flag);

    k_edge<<<(nE + EPB - 1) / EPB, 256, 0, stream>>>(ei, ew, We, att, xl, xr,
                                                     denom, aggnum, nE, flag);

    k_bnstats<<<200, 256, 0, stream>>>(aggnum, denom, bias, bnsum, bnsumsq, n, flag);

    int totalOut = n * D;
    k_final<<<(totalOut + 255) / 256, 256, 0, stream>>>(aggnum, denom, bias, gamma,
                                                        beta, bnsum, bnsumsq,
                                                        (float*)d_out, n, flag);
}